// Round 1
// baseline (691.329 us; speedup 1.0000x reference)
//
#include <hip/hip_runtime.h>

#define S 1024
#define D 64
#define R 16          // rows per block
#define SP (S + 4)    // padded LDS stride: 1028 floats = 4112 B (16B aligned, 4-bank row stagger)
#define BH 64         // B*H = 4*16

__global__ __launch_bounds__(256, 2)
void attn_fused_kernel(const float* __restrict__ q,
                       const float* __restrict__ k,      // [BH][D][S] (pre-transposed)
                       const float* __restrict__ v,      // [BH][S][D]
                       const float* __restrict__ prev,   // [BH][S][S]
                       const float* __restrict__ mask,   // [S][S] (broadcast over BH)
                       const float* __restrict__ scale_p,
                       float* __restrict__ out,          // [BH][S][D]
                       float* __restrict__ weights,      // [BH][S][S]
                       float* __restrict__ scores)       // [BH][S][S]
{
    __shared__ float q_lds[R][D];
    __shared__ float s_tile[R][SP];
    __shared__ float red_max[4][R];
    __shared__ float red_sum[4][R];

    const int tile = blockIdx.x;   // 0..63 row tile
    const int bh   = blockIdx.y;   // 0..63
    const int tid  = (int)threadIdx.x;
    const int lane = tid & 63;
    const int wid  = tid >> 6;
    const int r0   = tile * R;

    const float* qb = q    + (size_t)bh * S * D + (size_t)r0 * D;
    const float* kb = k    + (size_t)bh * D * S;
    const float* vb = v    + (size_t)bh * S * D;
    const float* pb = prev + (size_t)bh * S * S + (size_t)r0 * S;
    const float* mb = mask + (size_t)r0 * S;
    float* wout = weights + (size_t)bh * S * S + (size_t)r0 * S;
    float* sout = scores  + (size_t)bh * S * S + (size_t)r0 * S;
    float* oout = out     + (size_t)bh * S * D + (size_t)r0 * D;

    // ---- load q tile (16x64 = 1024 floats) via one float4 per thread ----
    {
        float4 qv = *(const float4*)(qb + (size_t)tid * 4);
        *(float4*)&q_lds[tid >> 4][(tid & 15) * 4] = qv;
    }
    __syncthreads();

    // ---- phase 1: QK^T. Each thread owns cols [t0, t0+4) for all 16 rows ----
    const int t0 = tid * 4;
    float acc[R][4];
#pragma unroll
    for (int r = 0; r < R; ++r) {
        acc[r][0] = 0.f; acc[r][1] = 0.f; acc[r][2] = 0.f; acc[r][3] = 0.f;
    }

    for (int dq = 0; dq < D / 4; ++dq) {
        const float* kp = kb + (size_t)(dq * 4) * S + t0;
        float4 k0 = *(const float4*)(kp);
        float4 k1 = *(const float4*)(kp + S);
        float4 k2 = *(const float4*)(kp + 2 * S);
        float4 k3 = *(const float4*)(kp + 3 * S);
#pragma unroll
        for (int r = 0; r < R; ++r) {
            float4 q4 = *(const float4*)&q_lds[r][dq * 4];
            acc[r][0] = fmaf(q4.w, k3.x, fmaf(q4.z, k2.x, fmaf(q4.y, k1.x, fmaf(q4.x, k0.x, acc[r][0]))));
            acc[r][1] = fmaf(q4.w, k3.y, fmaf(q4.z, k2.y, fmaf(q4.y, k1.y, fmaf(q4.x, k0.y, acc[r][1]))));
            acc[r][2] = fmaf(q4.w, k3.z, fmaf(q4.z, k2.z, fmaf(q4.y, k1.z, fmaf(q4.x, k0.z, acc[r][2]))));
            acc[r][3] = fmaf(q4.w, k3.w, fmaf(q4.z, k2.w, fmaf(q4.y, k1.w, fmaf(q4.x, k0.w, acc[r][3]))));
        }
    }

    // ---- epilogue: scale + prev + mask, write scores ----
    const float scale = *scale_p;
#pragma unroll
    for (int r = 0; r < R; ++r) {
        float4 p4 = *(const float4*)(pb + (size_t)r * S + t0);
        float4 m4 = *(const float4*)(mb + (size_t)r * S + t0);
        acc[r][0] = fmaf(acc[r][0], scale, p4.x + m4.x);
        acc[r][1] = fmaf(acc[r][1], scale, p4.y + m4.y);
        acc[r][2] = fmaf(acc[r][2], scale, p4.z + m4.z);
        acc[r][3] = fmaf(acc[r][3], scale, p4.w + m4.w);
        float4 s4 = { acc[r][0], acc[r][1], acc[r][2], acc[r][3] };
        *(float4*)(sout + (size_t)r * S + t0) = s4;
    }

    // ---- softmax over t (rows of 1024, spread across all 256 threads) ----
    // per-row max: wave butterfly then cross-wave via tiny LDS
    {
        float rmax[R];
#pragma unroll
        for (int r = 0; r < R; ++r) {
            float m = fmaxf(fmaxf(acc[r][0], acc[r][1]), fmaxf(acc[r][2], acc[r][3]));
#pragma unroll
            for (int off = 32; off > 0; off >>= 1)
                m = fmaxf(m, __shfl_xor(m, off));
            rmax[r] = m;
        }
        if (lane == 0) {
#pragma unroll
            for (int r = 0; r < R; ++r) red_max[wid][r] = rmax[r];
        }
    }
    __syncthreads();

    {
        float rsum[R];
#pragma unroll
        for (int r = 0; r < R; ++r) {
            float gm = fmaxf(fmaxf(red_max[0][r], red_max[1][r]),
                             fmaxf(red_max[2][r], red_max[3][r]));
            acc[r][0] = __expf(acc[r][0] - gm);
            acc[r][1] = __expf(acc[r][1] - gm);
            acc[r][2] = __expf(acc[r][2] - gm);
            acc[r][3] = __expf(acc[r][3] - gm);
            float ssum = (acc[r][0] + acc[r][1]) + (acc[r][2] + acc[r][3]);
#pragma unroll
            for (int off = 32; off > 0; off >>= 1)
                ssum += __shfl_xor(ssum, off);
            rsum[r] = ssum;
        }
        if (lane == 0) {
#pragma unroll
            for (int r = 0; r < R; ++r) red_sum[wid][r] = rsum[r];
        }
    }
    __syncthreads();

#pragma unroll
    for (int r = 0; r < R; ++r) {
        float gs = (red_sum[0][r] + red_sum[1][r]) + (red_sum[2][r] + red_sum[3][r]);
        float inv = 1.0f / gs;
        float4 w4 = { acc[r][0] * inv, acc[r][1] * inv, acc[r][2] * inv, acc[r][3] * inv };
        *(float4*)(wout + (size_t)r * S + t0) = w4;
        *(float4*)&s_tile[r][t0] = w4;
    }
    __syncthreads();

    // ---- phase 3: out = W @ V. Wave w owns rows [w*4, w*4+4); lane owns (row, 4 d) ----
    {
        const int prow = wid * 4 + (lane >> 4);   // 0..15
        const int d0   = (lane & 15) * 4;         // 0..60
        float ox = 0.f, oy = 0.f, oz = 0.f, ow = 0.f;
#pragma unroll 4
        for (int t = 0; t < S; t += 4) {
            float4 w4 = *(const float4*)&s_tile[prow][t];
            const float* vp = vb + (size_t)t * D + d0;
            float4 v0 = *(const float4*)(vp);
            float4 v1 = *(const float4*)(vp + D);
            float4 v2 = *(const float4*)(vp + 2 * D);
            float4 v3 = *(const float4*)(vp + 3 * D);
            ox = fmaf(w4.w, v3.x, fmaf(w4.z, v2.x, fmaf(w4.y, v1.x, fmaf(w4.x, v0.x, ox))));
            oy = fmaf(w4.w, v3.y, fmaf(w4.z, v2.y, fmaf(w4.y, v1.y, fmaf(w4.x, v0.y, oy))));
            oz = fmaf(w4.w, v3.z, fmaf(w4.z, v2.z, fmaf(w4.y, v1.z, fmaf(w4.x, v0.z, oz))));
            ow = fmaf(w4.w, v3.w, fmaf(w4.z, v2.w, fmaf(w4.y, v1.w, fmaf(w4.x, v0.w, ow))));
        }
        float4 o4 = { ox, oy, oz, ow };
        *(float4*)(oout + (size_t)prow * D + d0) = o4;
    }
}

extern "C" void kernel_launch(void* const* d_in, const int* in_sizes, int n_in,
                              void* d_out, int out_size, void* d_ws, size_t ws_size,
                              hipStream_t stream) {
    (void)in_sizes; (void)n_in; (void)out_size; (void)d_ws; (void)ws_size;
    const float* q     = (const float*)d_in[0];
    const float* k     = (const float*)d_in[1];
    const float* v     = (const float*)d_in[2];
    const float* prev  = (const float*)d_in[3];
    const float* mask  = (const float*)d_in[4];
    const float* scale = (const float*)d_in[5];

    float* out     = (float*)d_out;                       // 4*16*1024*64   = 4194304
    float* weights = out + (size_t)4 * 16 * 1024 * 64;    // 4*16*1024*1024 = 67108864
    float* scores  = weights + (size_t)4 * 16 * 1024 * 1024;

    dim3 grid(S / R, BH);   // (64, 64)
    attn_fused_kernel<<<grid, 256, 0, stream>>>(q, k, v, prev, mask, scale,
                                                out, weights, scores);
}